// Round 1
// baseline (135.585 us; speedup 1.0000x reference)
//
#include <hip/hip_runtime.h>

#define B_DIM 256
#define I_DIM 128
#define O_DIM 128
#define H_DIM 32
#define F_DIM 7
#define ICHUNK 16
#define NCHUNK (I_DIM / ICHUNK)   // 8

// Block = 256 threads: hs = tid>>6 (4 h-slices of 8), bg = tid&63 (b-group;
// thread covers b = bg + 64k, k=0..3 -> whole B=256 per block).
// Each block: one output column o, one chunk of 16 i's.
__global__ __launch_bounds__(256, 4)
void fcnkan_kernel(const float* __restrict__ x,
                   const float* __restrict__ W1,
                   const float* __restrict__ W2,
                   const float* __restrict__ B1,
                   const float* __restrict__ B2,
                   float* __restrict__ out) {
    // [il][h][8]: w0..w6, then B1 in slot 7 (float4-pair friendly, broadcast reads)
    __shared__ float w1b1[ICHUNK * H_DIM * 8];      // 16 KiB
    __shared__ float w2s[ICHUNK * H_DIM];           // 2 KiB
    __shared__ float b2s[ICHUNK];
    __shared__ float red[4][B_DIM];                 // 4 KiB, hs-reduction

    const int tid = threadIdx.x;
    const int o   = blockIdx.x;
    const int ic0 = blockIdx.y * ICHUNK;

    // ---- stage W1 (packed) ----
    for (int e = tid; e < ICHUNK * H_DIM * F_DIM; e += 256) {
        int il = e / (H_DIM * F_DIM);
        int r  = e - il * (H_DIM * F_DIM);
        int h  = r / F_DIM;
        int f  = r - h * F_DIM;
        w1b1[(il * H_DIM + h) * 8 + f] =
            W1[(size_t)((ic0 + il) * O_DIM + o) * (H_DIM * F_DIM) + r];
    }
    // ---- stage B1 (slot 7) and W2 ----
    for (int e = tid; e < ICHUNK * H_DIM; e += 256) {
        int il = e >> 5;
        int h  = e & 31;
        int io = (ic0 + il) * O_DIM + o;
        w1b1[(il * H_DIM + h) * 8 + 7] = B1[io * H_DIM + h];
        w2s[e]                         = W2[io * H_DIM + h];
    }
    if (tid < ICHUNK) b2s[tid] = B2[(ic0 + tid) * O_DIM + o];
    __syncthreads();

    const int hs = tid >> 6;   // h-slice: h in [hs*8, hs*8+8)
    const int bg = tid & 63;   // b-group: b = bg + 64k

    float acc[4] = {0.f, 0.f, 0.f, 0.f};

    for (int il = 0; il < ICHUNK; ++il) {
        // features for this thread's 4 b's: [x, sin x, sin 2x, sin 4x, cos x, cos 2x, cos 4x]
        float f0[4], f1[4], f2[4], f3[4], f4[4], f5[4], f6[4];
        #pragma unroll
        for (int k = 0; k < 4; ++k) {
            float xv = x[(size_t)(bg + 64 * k) * I_DIM + ic0 + il];
            float s1 = __sinf(xv);
            float c1 = __cosf(xv);
            float s2 = 2.f * s1 * c1;
            float c2 = 1.f - 2.f * s1 * s1;
            float s4 = 2.f * s2 * c2;
            float c4 = 1.f - 2.f * s2 * s2;
            f0[k] = xv; f1[k] = s1; f2[k] = s2; f3[k] = s4;
            f4[k] = c1; f5[k] = c2; f6[k] = c4;
        }
        const float4* wrow  = reinterpret_cast<const float4*>(w1b1 + il * H_DIM * 8);
        const float*  w2row = w2s + il * H_DIM + hs * 8;
        #pragma unroll
        for (int h = 0; h < 8; ++h) {
            float4 wa  = wrow[(hs * 8 + h) * 2];       // w0..w3
            float4 wb  = wrow[(hs * 8 + h) * 2 + 1];   // w4,w5,w6,b1
            float  w2v = w2row[h];
            #pragma unroll
            for (int k = 0; k < 4; ++k) {
                float z = wb.w;
                z = fmaf(wa.x, f0[k], z);
                z = fmaf(wa.y, f1[k], z);
                z = fmaf(wa.z, f2[k], z);
                z = fmaf(wa.w, f3[k], z);
                z = fmaf(wb.x, f4[k], z);
                z = fmaf(wb.y, f5[k], z);
                z = fmaf(wb.z, f6[k], z);
                // silu(z) = z / (1 + e^-z)
                float ev = __expf(-z);
                float sg = __builtin_amdgcn_rcpf(1.f + ev);
                acc[k] = fmaf(z * sg, w2v, acc[k]);
            }
        }
    }

    // ---- reduce over the 4 h-slices ----
    #pragma unroll
    for (int k = 0; k < 4; ++k) red[hs][bg + 64 * k] = acc[k];
    __syncthreads();

    // per-chunk B2 contribution (same for every b)
    float b2c = 0.f;
    #pragma unroll
    for (int il = 0; il < ICHUNK; ++il) b2c += b2s[il];

    float total = red[0][tid] + red[1][tid] + red[2][tid] + red[3][tid] + b2c;
    atomicAdd(&out[(size_t)tid * O_DIM + o], total);
}

extern "C" void kernel_launch(void* const* d_in, const int* in_sizes, int n_in,
                              void* d_out, int out_size, void* d_ws, size_t ws_size,
                              hipStream_t stream) {
    const float* x  = (const float*)d_in[0];
    const float* W1 = (const float*)d_in[1];
    const float* W2 = (const float*)d_in[2];
    const float* B1 = (const float*)d_in[3];
    const float* B2 = (const float*)d_in[4];
    float* out = (float*)d_out;

    hipMemsetAsync(out, 0, (size_t)out_size * sizeof(float), stream);
    dim3 grid(O_DIM, NCHUNK);
    fcnkan_kernel<<<grid, 256, 0, stream>>>(x, W1, W2, B1, B2, out);
}